// Round 9
// baseline (61.897 us; speedup 1.0000x reference)
//
#include <hip/hip_runtime.h>

// LCALayer: per-row (N=2e6, D=8) elementwise update.
// recur = sum(activities @ gamma) = -0.7 * rowsum(activities)
// active = all(|activities| < 1) ? 1 : 0
// pre = pa + (inp - 0.1*pa + recur) * active * 0.01 + nr * active * sqrt(0.001)
// act = relu(pre)
//
// R8 post-mortem: chunk-per-2-lanes (no LDS) == R7 LDS-repack == 60.8-61.0 us.
// Effective 6.4 TB/s logical BW. Distinguishing fabric-bound vs latency-bound:
// R9 = 3 chunks/thread (12 outstanding 16B loads, ~44 VGPR — below the
// 64-VGPR occupancy cliff that killed R6 at 88 VGPR). Neutral => fabric-bound
// => R8 is the roofline.

#define THRESHOLD 1.0f
#define LEAK 0.1f
#define TSTEP 0.01f
#define SQRT_STEP 0.031622776601683794f  // sqrt(0.001)

typedef float vfloat4 __attribute__((ext_vector_type(4)));

#define CHUNKS_PER_THREAD 3

__device__ __forceinline__ void lca_chunk(
    const vfloat4& av, const vfloat4& iv4,
    const vfloat4& pv4, const vfloat4& nv4,
    vfloat4& pr4, vfloat4& ac4, float& active_out)
{
    float a[4] = {av.x, av.y, av.z, av.w};
    float s_loc = a[0] + a[1] + a[2] + a[3];
    bool  below = (fabsf(a[0]) < THRESHOLD) && (fabsf(a[1]) < THRESHOLD) &&
                  (fabsf(a[2]) < THRESHOLD) && (fabsf(a[3]) < THRESHOLD);
    float m_loc = below ? 1.0f : 0.0f;
    // pair exchange with the other half of the row (lane ^ 1)
    float s_oth = __shfl_xor(s_loc, 1, 64);
    float m_oth = __shfl_xor(m_loc, 1, 64);
    const float S      = s_loc + s_oth;
    const float active = m_loc * m_oth;
    const float recur  = -0.7f * S;

    const float ts_a = active * TSTEP;
    const float ns_a = active * SQRT_STEP;

    float iv[4] = {iv4.x, iv4.y, iv4.z, iv4.w};
    float pv[4] = {pv4.x, pv4.y, pv4.z, pv4.w};
    float nv[4] = {nv4.x, nv4.y, nv4.z, nv4.w};

    float pr[4], ac[4];
#pragma unroll
    for (int j = 0; j < 4; ++j) {
        float x = iv[j] - LEAK * pv[j] + recur;
        float p = pv[j] + x * ts_a + nv[j] * ns_a;
        pr[j] = p;
        ac[j] = fmaxf(p, 0.0f);
    }
    pr4 = (vfloat4){pr[0], pr[1], pr[2], pr[3]};
    ac4 = (vfloat4){ac[0], ac[1], ac[2], ac[3]};
    active_out = active;
}

__global__ __launch_bounds__(256) void lca_kernel(
    const float* __restrict__ inp,
    const float* __restrict__ pa,
    const float* __restrict__ acts,
    const float* __restrict__ nr,
    float* __restrict__ out_pre,
    float* __restrict__ out_act,
    float* __restrict__ out_active,
    int nchunks)  // = 2 * n_rows
{
    // chunk c covers floats [4c, 4c+4) = row c>>1, half c&1.
    // pairs (c, c^1) always land on lanes (tid, tid^1) of the same wave.
    const int c0 = blockIdx.x * (256 * CHUNKS_PER_THREAD) + threadIdx.x;

    int  c[CHUNKS_PER_THREAD];
    bool ok[CHUNKS_PER_THREAD];
    size_t b[CHUNKS_PER_THREAD];
#pragma unroll
    for (int k = 0; k < CHUNKS_PER_THREAD; ++k) {
        c[k]  = c0 + k * 256;
        ok[k] = c[k] < nchunks;
        b[k]  = (size_t)c[k] * 4;
    }

    // all loads up front (up to 12 x 16B outstanding, dense 1KB wave spans)
    vfloat4 va[CHUNKS_PER_THREAD], vi[CHUNKS_PER_THREAD];
    vfloat4 vp[CHUNKS_PER_THREAD], vn[CHUNKS_PER_THREAD];
#pragma unroll
    for (int k = 0; k < CHUNKS_PER_THREAD; ++k) {
        if (ok[k]) {
            va[k] = *reinterpret_cast<const vfloat4*>(acts + b[k]);
            vi[k] = *reinterpret_cast<const vfloat4*>(inp + b[k]);
            vp[k] = *reinterpret_cast<const vfloat4*>(pa + b[k]);
            vn[k] = *reinterpret_cast<const vfloat4*>(nr + b[k]);
        }
    }

#pragma unroll
    for (int k = 0; k < CHUNKS_PER_THREAD; ++k) {
        vfloat4 pr4, ac4; float act;
        lca_chunk(va[k], vi[k], vp[k], vn[k], pr4, ac4, act);
        if (ok[k]) {
            __builtin_nontemporal_store(pr4, reinterpret_cast<vfloat4*>(out_pre + b[k]));
            __builtin_nontemporal_store(ac4, reinterpret_cast<vfloat4*>(out_act + b[k]));
            if ((c[k] & 1) == 0)
                __builtin_nontemporal_store(act, out_active + (c[k] >> 1));
        }
    }
}

extern "C" void kernel_launch(void* const* d_in, const int* in_sizes, int n_in,
                              void* d_out, int out_size, void* d_ws, size_t ws_size,
                              hipStream_t stream) {
    const float* inp  = (const float*)d_in[0];
    const float* pa   = (const float*)d_in[1];
    const float* acts = (const float*)d_in[2];
    const float* nr   = (const float*)d_in[3];

    const int n = in_sizes[0] / 8;   // 2,000,000 rows
    const int nchunks = n * 2;       // 4-float chunks

    float* out = (float*)d_out;
    float* out_pre    = out;                    // [n, 8]
    float* out_act    = out + (size_t)n * 8;    // [n, 8]
    float* out_active = out + (size_t)n * 16;   // [n, 1]

    const int block = 256;
    const int chunks_per_block = block * CHUNKS_PER_THREAD;  // 768
    const int grid = (nchunks + chunks_per_block - 1) / chunks_per_block;
    lca_kernel<<<grid, block, 0, stream>>>(inp, pa, acts, nr,
                                           out_pre, out_act, out_active, nchunks);
}

// Round 10
// 60.009 us; speedup vs baseline: 1.0315x; 1.0315x over previous
//
#include <hip/hip_runtime.h>

// LCALayer: per-row (N=2e6, D=8) elementwise update. FINAL (R8 revert).
// recur = sum(activities @ gamma) = -0.7 * rowsum(activities)
// active = all(|activities| < 1) ? 1 : 0
// pre = pa + (inp - 0.1*pa + recur) * active * 0.01 + nr * active * sqrt(0.001)
// act = relu(pre)
//
// Trajectory: 78.4 (R0 naive-vectorized) -> 72.7 (NT stores; L2 write-
// allocate pollution costs more than +17MB HBM writes) -> 67.0 (2 rows/
// thread ILP) -> 60.8 (dense 1KB wave-span stores, first via LDS repack
// (R7), then natively via 2-lanes-per-row layout (R8, this kernel)).
// R9 (12 outstanding loads) neutral => fabric/L3-path bound at ~6.4 TB/s
// logical (> 6.3 TB/s copy ceiling; FETCH 125MB/WRITE 133MB at floors).

#define THRESHOLD 1.0f
#define LEAK 0.1f
#define TSTEP 0.01f
#define SQRT_STEP 0.031622776601683794f  // sqrt(0.001)

typedef float vfloat4 __attribute__((ext_vector_type(4)));

__device__ __forceinline__ void lca_chunk(
    const vfloat4& av, const vfloat4& iv4,
    const vfloat4& pv4, const vfloat4& nv4,
    vfloat4& pr4, vfloat4& ac4, float& active_out)
{
    float a[4] = {av.x, av.y, av.z, av.w};
    // local half-row reduction
    float s_loc = a[0] + a[1] + a[2] + a[3];
    bool  below = (fabsf(a[0]) < THRESHOLD) && (fabsf(a[1]) < THRESHOLD) &&
                  (fabsf(a[2]) < THRESHOLD) && (fabsf(a[3]) < THRESHOLD);
    float m_loc = below ? 1.0f : 0.0f;
    // pair exchange with the other half of the row (lane ^ 1)
    float s_oth = __shfl_xor(s_loc, 1, 64);
    float m_oth = __shfl_xor(m_loc, 1, 64);
    const float S      = s_loc + s_oth;
    const float active = m_loc * m_oth;
    const float recur  = -0.7f * S;

    const float ts_a = active * TSTEP;
    const float ns_a = active * SQRT_STEP;

    float iv[4] = {iv4.x, iv4.y, iv4.z, iv4.w};
    float pv[4] = {pv4.x, pv4.y, pv4.z, pv4.w};
    float nv[4] = {nv4.x, nv4.y, nv4.z, nv4.w};

    float pr[4], ac[4];
#pragma unroll
    for (int j = 0; j < 4; ++j) {
        float x = iv[j] - LEAK * pv[j] + recur;
        float p = pv[j] + x * ts_a + nv[j] * ns_a;
        pr[j] = p;
        ac[j] = fmaxf(p, 0.0f);
    }
    pr4 = (vfloat4){pr[0], pr[1], pr[2], pr[3]};
    ac4 = (vfloat4){ac[0], ac[1], ac[2], ac[3]};
    active_out = active;
}

__global__ __launch_bounds__(256) void lca_kernel(
    const float* __restrict__ inp,
    const float* __restrict__ pa,
    const float* __restrict__ acts,
    const float* __restrict__ nr,
    float* __restrict__ out_pre,
    float* __restrict__ out_act,
    float* __restrict__ out_active,
    int nchunks)  // = 2 * n_rows
{
    // chunk c covers floats [4c, 4c+4) = row c>>1, half c&1.
    // pairs (c, c^1) always land on lanes (tid, tid^1) of the same wave.
    const int cA = blockIdx.x * 512 + threadIdx.x;
    const int cB = cA + 256;
    const bool okA = cA < nchunks;
    const bool okB = cB < nchunks;
    const size_t bA = (size_t)cA * 4;
    const size_t bB = (size_t)cB * 4;

    // all loads up front (8 x 16B in flight, dense 1KB per wave-instruction)
    vfloat4 Aa{}, Ai{}, Ap{}, An{}, Ba{}, Bi{}, Bp{}, Bn{};
    if (okA) {
        Aa = *reinterpret_cast<const vfloat4*>(acts + bA);
        Ai = *reinterpret_cast<const vfloat4*>(inp + bA);
        Ap = *reinterpret_cast<const vfloat4*>(pa + bA);
        An = *reinterpret_cast<const vfloat4*>(nr + bA);
    }
    if (okB) {
        Ba = *reinterpret_cast<const vfloat4*>(acts + bB);
        Bi = *reinterpret_cast<const vfloat4*>(inp + bB);
        Bp = *reinterpret_cast<const vfloat4*>(pa + bB);
        Bn = *reinterpret_cast<const vfloat4*>(nr + bB);
    }

    {
        vfloat4 pr4, ac4; float act;
        lca_chunk(Aa, Ai, Ap, An, pr4, ac4, act);
        if (okA) {
            __builtin_nontemporal_store(pr4, reinterpret_cast<vfloat4*>(out_pre + bA));
            __builtin_nontemporal_store(ac4, reinterpret_cast<vfloat4*>(out_act + bA));
            if ((cA & 1) == 0)
                __builtin_nontemporal_store(act, out_active + (cA >> 1));
        }
    }
    {
        vfloat4 pr4, ac4; float act;
        lca_chunk(Ba, Bi, Bp, Bn, pr4, ac4, act);
        if (okB) {
            __builtin_nontemporal_store(pr4, reinterpret_cast<vfloat4*>(out_pre + bB));
            __builtin_nontemporal_store(ac4, reinterpret_cast<vfloat4*>(out_act + bB));
            if ((cB & 1) == 0)
                __builtin_nontemporal_store(act, out_active + (cB >> 1));
        }
    }
}

extern "C" void kernel_launch(void* const* d_in, const int* in_sizes, int n_in,
                              void* d_out, int out_size, void* d_ws, size_t ws_size,
                              hipStream_t stream) {
    const float* inp  = (const float*)d_in[0];
    const float* pa   = (const float*)d_in[1];
    const float* acts = (const float*)d_in[2];
    const float* nr   = (const float*)d_in[3];

    const int n = in_sizes[0] / 8;   // 2,000,000 rows
    const int nchunks = n * 2;       // 4-float chunks

    float* out = (float*)d_out;
    float* out_pre    = out;                    // [n, 8]
    float* out_act    = out + (size_t)n * 8;    // [n, 8]
    float* out_active = out + (size_t)n * 16;   // [n, 1]

    const int block = 256;
    const int grid = (nchunks + 511) / 512;     // 2 chunks per thread
    lca_kernel<<<grid, block, 0, stream>>>(inp, pa, acts, nr,
                                           out_pre, out_act, out_active, nchunks);
}